// Round 7
// baseline (115.510 us; speedup 1.0000x reference)
//
#include <hip/hip_runtime.h>

// MedianPool2d 3x3, stride 1, reflect pad, [8,8,512,512] fp32.
// Dense-coalesced: lane owns 4 cols (16 B stride) -> every global dwordx4 is a
// fully dense 1 KB wave transaction. Wave spans half a row; 8 output rows per
// thread. 5-slot rolling row buffer with prefetch distance 2 (two 1 KB row
// loads in flight per wave). Halos via 2 scalar L1-hit loads/row. Plain
// (cache-coherent) stores. XCD-aware swizzle: all 32 blocks of one image land
// on the same XCD so row re-reads stay in that XCD's 4 MiB L2.

#define MP_W 512
#define MP_H 512

typedef float floatx4 __attribute__((ext_vector_type(4)));

__device__ __forceinline__ void mnmx(float& a, float& b) {
    const float t = fminf(a, b);
    b = fmaxf(a, b);
    a = t;
}

__device__ __forceinline__ float med3f(float a, float b, float c) {
    return fmaxf(fminf(a, b), fminf(fmaxf(a, b), c));
}

__global__ __launch_bounds__(256) void median3x3_kernel(const float* __restrict__ x,
                                                        float* __restrict__ out) {
    const int lane  = threadIdx.x & 63;
    const int wslot = threadIdx.x >> 6;          // wave within block: 0..3
    // XCD swizzle: blocks stripe over 8 XCDs as (blockIdx % 8); give each XCD
    // 8 whole images so halo-row re-reads hit the local L2.
    const int b    = blockIdx.x;
    const int xcd  = b & 7;
    const int idx  = b >> 3;                     // 0..255
    const int img  = ((idx >> 5) << 3) | xcd;    // image 0..63
    const int j    = idx & 31;                   // block-in-image 0..31
    const int w    = (j << 2) | wslot;           // wave-in-image 0..127
    const int hf   = w & 1;                      // row half
    const int rg   = w >> 1;                     // 8-row group 0..63
    const int y0   = rg << 3;
    const int x0   = (hf << 8) | (lane << 2);    // dense: lane-stride 16 B

    // reflect-adjusted halo offsets relative to rp = row base + x0
    const int off_l = (x0 == 0)        ? 1 : -1;   // -1 -> 1
    const int off_r = (x0 == MP_W - 4) ? 2 : 4;    // 512 -> 510

    const float* base  = x   + ((size_t)img << 18);
    float*       obase = out + ((size_t)img << 18) + (size_t)y0 * MP_W + x0;

    auto row_ptr = [&](int yy) -> const float* {
        yy = (yy < 0) ? -yy : (yy >= MP_H ? 2 * MP_H - 2 - yy : yy);  // reflect
        return base + (size_t)yy * MP_W + x0;
    };

    // 5-slot rolling buffer; input row (y0-1+m) lives in slot m%5.
    floatx4 bufV[5];
    float   bufL[5], bufR[5];

    #pragma unroll
    for (int k = 0; k < 4; ++k) {    // prologue: input rows y0-1 .. y0+2
        const float* rp = row_ptr(y0 - 1 + k);
        bufV[k] = *(const floatx4*)rp;
        bufL[k] = rp[off_l];
        bufR[k] = rp[off_r];
    }

    #pragma unroll
    for (int r = 0; r < 8; ++r) {
        // prefetch input row y0+r+3 (distance 2) into slot (r+4)%5
        if (r < 6) {
            const int s = (r + 4) % 5;
            const float* rp = row_ptr(y0 + r + 3);
            bufV[s] = *(const floatx4*)rp;
            bufL[s] = rp[off_l];
            bufR[s] = rp[off_r];
        }

        // window rows for output row y0+r: slots r%5, (r+1)%5, (r+2)%5
        float v[3][6];
        #pragma unroll
        for (int k = 0; k < 3; ++k) {
            const int s = (r + k) % 5;
            const floatx4 a = bufV[s];
            v[k][0] = bufL[s];
            v[k][1] = a.x; v[k][2] = a.y; v[k][3] = a.z; v[k][4] = a.w;
            v[k][5] = bufR[s];
        }

        // sort each vertical column triple (shared by the 3 horizontal windows)
        float lo[6], mi[6], hi[6];
        #pragma unroll
        for (int jj = 0; jj < 6; ++jj) {
            float a = v[0][jj], bb = v[1][jj], c = v[2][jj];
            mnmx(a, bb); mnmx(a, c); mnmx(bb, c);
            lo[jj] = a; mi[jj] = bb; hi[jj] = c;
        }

        float res[4];
        #pragma unroll
        for (int jj = 0; jj < 4; ++jj) {
            const float L = fmaxf(fmaxf(lo[jj], lo[jj + 1]), lo[jj + 2]);
            const float M = med3f(mi[jj], mi[jj + 1], mi[jj + 2]);
            const float H = fminf(fminf(hi[jj], hi[jj + 1]), hi[jj + 2]);
            res[jj] = med3f(L, M, H);
        }

        floatx4 o = {res[0], res[1], res[2], res[3]};
        *(floatx4*)(obase + (size_t)r * MP_W) = o;
    }
}

extern "C" void kernel_launch(void* const* d_in, const int* in_sizes, int n_in,
                              void* d_out, int out_size, void* d_ws, size_t ws_size,
                              hipStream_t stream) {
    const float* x = (const float*)d_in[0];
    float* out = (float*)d_out;
    // 32 outputs per thread (4 cols x 8 rows) -> 524288 threads -> 2048 blocks
    const int n_threads = out_size / 32;
    const int block = 256;
    const int grid = n_threads / block;   // 2048
    median3x3_kernel<<<grid, block, 0, stream>>>(x, out);
}